// Round 2
// baseline (657.239 us; speedup 1.0000x reference)
//
#include <hip/hip_runtime.h>

#define T_ 16
#define E_ 64
#define V_ 96
#define L_ 4

typedef unsigned int u32;
typedef unsigned short u16;
typedef __attribute__((ext_vector_type(8))) short bf16x8;
typedef __attribute__((ext_vector_type(4))) float f32x4;

#define MFMA(a, b, c) __builtin_amdgcn_mfma_f32_16x16x32_bf16(a, b, c, 0, 0, 0)

// ws layout (bf16/short elements): B-operand layout [n][k] per matrix
#define OFF_TQ 0
#define OFF_TK 16384
#define OFF_TV 32768
#define OFF_TWO 49152
#define OFF_TW1 65536
#define OFF_TW2 81920
#define OFF_TWOUT 98304
#define PREP_TOT 104448

__device__ __forceinline__ short f2b_rne(float f) {  // fp32 -> bf16 RNE (prep only)
  u32 u = __float_as_uint(f);
  u32 r = (u + 0x7fffu + ((u >> 16) & 1u)) >> 16;
  return (short)r;
}
__device__ __forceinline__ float b2f(short s) {
  return __uint_as_float(((u32)(u16)s) << 16);
}
// round-half-up bf16 pack: low short = bf16(a), high short = bf16(b). 3 VALU.
__device__ __forceinline__ u32 pack2_ru(float a, float b) {
  return __builtin_amdgcn_perm(__float_as_uint(a) + 0x8000u,
                               __float_as_uint(b) + 0x8000u, 0x03020706u);
}
// single-element round-half-up bf16 (same numerics as pack2_ru) for ds_write_b16
__device__ __forceinline__ short b16_ru(float f) {
  return (short)((__float_as_uint(f) + 0x8000u) >> 16);
}

// 16-lane-row reduction via DPP row_ror adds: pure VALU, zero LDS-pipe traffic.
template <int N>
__device__ __forceinline__ float ror_add(float x) {
  int y = __builtin_amdgcn_update_dpp(0, __float_as_int(x), 0x120 + N, 0xF, 0xF,
                                      true);
  return x + __int_as_float(y);
}
__device__ __forceinline__ float sum16(float x) {
  x = ror_add<8>(x);
  x = ror_add<4>(x);
  x = ror_add<2>(x);
  x = ror_add<1>(x);
  return x;
}

__global__ void __launch_bounds__(256) prep_weights(
    const float* __restrict__ Wq, const float* __restrict__ Wk,
    const float* __restrict__ Wv, const float* __restrict__ Wo,
    const float* __restrict__ W1, const float* __restrict__ W2,
    const float* __restrict__ Wout, short* __restrict__ wpo) {
  int id = blockIdx.x * 256 + threadIdx.x;
  if (id >= PREP_TOT) return;
  float v;
  if (id < OFF_TWO) {                       // TQ/TK/TV: n = h*16+kq, k = e
    int which = id >> 14;                   // 0=Q,1=K,2=V
    int r = id & 16383;
    int l = r >> 12, n = (r >> 6) & 63, e = r & 63;
    int h = n >> 4, kq = n & 15;
    const float* W = which == 0 ? Wq : (which == 1 ? Wk : Wv);
    v = W[((l * 4 + h) * 64 + e) * 16 + kq];
  } else if (id < OFF_TWOUT) {              // TWo/TW1/TW2: n = out col, k = e
    int id2 = id - OFF_TWO;
    int which = id2 >> 14;                  // 0=Wo,1=W1,2=W2
    int r = id2 & 16383;
    int l = r >> 12, n = (r >> 6) & 63, e = r & 63;
    const float* W = which == 0 ? Wo : (which == 1 ? W1 : W2);
    v = W[(l * 64 + e) * 64 + n];
  } else {                                  // TWout: n = vocab col, k = e
    int r = id - OFF_TWOUT;
    int n = r >> 6, e = r & 63;
    v = Wout[e * 96 + n];
  }
  wpo[id] = f2b_rne(v);
}

// LayerNorm over 64 cols held as 4 n-regs x 16 lanes (same qq group), rows r.
__device__ __forceinline__ void ln16(float vals[4][4]) {
#pragma unroll
  for (int r = 0; r < 4; ++r) {
    float s = vals[0][r] + vals[1][r] + vals[2][r] + vals[3][r];
    s = sum16(s);
    float mean = s * 0.015625f;
    float vv = 0.f;
#pragma unroll
    for (int n = 0; n < 4; ++n) { float d = vals[n][r] - mean; vv = fmaf(d, d, vv); }
    vv = sum16(vv);
    float rst = rsqrtf(vv * 0.015625f + 1e-5f);
#pragma unroll
    for (int n = 0; n < 4; ++n) vals[n][r] = (vals[n][r] - mean) * rst;
  }
}

// 256 threads = 4 waves; wave w handles sequence blockIdx.x*4+w. No
// __syncthreads: LDS is wave-private, DS pipe is in-order per wave.
// TWO arenas per wave (was 3) -> 18432 B/block -> 8 blocks/CU -> 32 waves/CU.
// Time-multiplex: cur: x -> q -> p -> ob -> h1 ; oth: k -> vT -> x1 -> x(next).
// Arenas ping-pong each layer; cols 64..71 of both stay zero (A-frag upper-K pad).
__global__ void __launch_bounds__(256, 8) bert_mfma(
    const int* __restrict__ data,
    const float* __restrict__ tok_emb, const float* __restrict__ pos_emb,
    const float* __restrict__ bo, const float* __restrict__ ln1g,
    const float* __restrict__ ln1b, const float* __restrict__ ln2g,
    const float* __restrict__ ln2b, const float* __restrict__ b1,
    const float* __restrict__ b2, const float* __restrict__ bout,
    const short* __restrict__ wp, float* __restrict__ out) {
  __shared__ __align__(16) short R[4][2][16][72];

  const int w = threadIdx.x >> 6;
  const int lane = threadIdx.x & 63;
  const int m = lane & 15;   // A-row t / B-row / C-col
  const int qq = lane >> 4;  // k-chunk for frags; C rows qq*4+r
  const int seq = blockIdx.x * 4 + w;

  short(*cur)[72] = R[w][0];
  short(*oth)[72] = R[w][1];

  // zero cols 64..71 of BOTH arenas: A-frag upper-K lanes (qq>=2) read here -> 0
  if (lane < 16) {
    *(float4*)&R[w][0][lane][64] = make_float4(0.f, 0.f, 0.f, 0.f);
    *(float4*)&R[w][1][lane][64] = make_float4(0.f, 0.f, 0.f, 0.f);
  }

  // ---- embedding: x = tok_emb[data] + pos_emb -> cur bf16 [t][e] ----
  {
    const int t = lane >> 2;
    const int c0 = (lane & 3) * 16;
    const int tok = data[seq * T_ + t];
    const float4* tp = (const float4*)(tok_emb + tok * E_ + c0);
    const float4* pp = (const float4*)(pos_emb + t * E_ + c0);
    u32 buf[8];
#pragma unroll
    for (int q = 0; q < 4; ++q) {
      float4 a = tp[q], b = pp[q];
      buf[q * 2 + 0] = pack2_ru(a.x + b.x, a.y + b.y);
      buf[q * 2 + 1] = pack2_ru(a.z + b.z, a.w + b.w);
    }
    ((bf16x8*)&cur[t][c0])[0] = ((bf16x8*)buf)[0];
    *(bf16x8*)&cur[t][c0 + 8] = ((bf16x8*)(buf + 4))[0];
  }

  // residual stream, C-layout regs: xres[n][r] = x[qq*4+r][n*16+m]
  float xres[4][4];
#pragma unroll
  for (int n = 0; n < 4; ++n)
#pragma unroll
    for (int r = 0; r < 4; ++r) xres[n][r] = b2f(cur[qq * 4 + r][n * 16 + m]);

  const short s1b = (short)0x3F80;
  const bf16x8 ones8 = {s1b, s1b, s1b, s1b, s1b, s1b, s1b, s1b};
  const f32x4 z4 = {0.f, 0.f, 0.f, 0.f};
  const int hselA = (qq < 2) ? 16 : 0;               // head stride for A-frag
  const int aoffA = (qq < 2) ? ((qq & 1) * 8) : 64;  // qq>=2 -> zero cols
  const int boff = (qq & 1) * 8;  // B-frag k>=16 multiplied by A zeros

#pragma unroll 1
  for (int l = 0; l < L_; ++l) {
    const short* TQ = wp + OFF_TQ + l * 4096;
    const short* TK = wp + OFF_TK + l * 4096;
    const short* TV = wp + OFF_TV + l * 4096;
    const short* TWO = wp + OFF_TWO + l * 4096;
    const short* TW1 = wp + OFF_TW1 + l * 4096;
    const short* TW2 = wp + OFF_TW2 + l * 4096;

    // phase 1: x A-frags to regs (x in LDS dead afterwards)
    bf16x8 ax0 = *(const bf16x8*)&cur[m][qq * 8];
    bf16x8 ax1 = *(const bf16x8*)&cur[m][32 + qq * 8];

    // phase 2a: Q,K all heads (16 MFMAs); q -> cur (over x), k -> oth
#pragma unroll
    for (int h = 0; h < 4; ++h) {
      const int bn = (h * 16 + m) * 64 + qq * 8;
      bf16x8 bq0 = *(const bf16x8*)(TQ + bn), bq1 = *(const bf16x8*)(TQ + bn + 32);
      bf16x8 bk0 = *(const bf16x8*)(TK + bn), bk1 = *(const bf16x8*)(TK + bn + 32);
      f32x4 qa = MFMA(ax0, bq0, z4); qa = MFMA(ax1, bq1, qa);
      f32x4 ka = MFMA(ax0, bk0, z4); ka = MFMA(ax1, bk1, ka);
#pragma unroll
      for (int r = 0; r < 4; ++r) {
        cur[qq * 4 + r][h * 16 + m] = b16_ru(qa[r]);
        oth[qq * 4 + r][h * 16 + m] = b16_ru(ka[r]);
      }
    }

    // phase 3: S_h = q k^T (A zero-cols give K 16..31 = 0)
    f32x4 sc[4];
#pragma unroll
    for (int h = 0; h < 4; ++h) {
      bf16x8 aq = *(const bf16x8*)&cur[m][h * hselA + aoffA];
      bf16x8 bk = *(const bf16x8*)&oth[m][h * 16 + boff];
      sc[h] = MFMA(aq, bk, z4);
    }

    // phase 2b: V (8 MFMAs, independent of phase 3) -> vT into oth (over k;
    // DS pipe is in-order per wave, so these stores queue after phase-3 reads)
#pragma unroll
    for (int h = 0; h < 4; ++h) {
      const int bn = (h * 16 + m) * 64 + qq * 8;
      bf16x8 bv0 = *(const bf16x8*)(TV + bn), bv1 = *(const bf16x8*)(TV + bn + 32);
      f32x4 va = MFMA(ax0, bv0, z4); va = MFMA(ax1, bv1, va);
      // vT[kd][h*16+t]: 4 consecutive t in-lane -> one b64
      *(uint2*)&oth[m][h * 16 + qq * 4] =
          make_uint2(pack2_ru(va[0], va[1]), pack2_ru(va[2], va[3]));
    }

    // phase 4: p_un = exp(S/4) (no max-sub: |S| << 1) -> cur (over q)
#pragma unroll
    for (int h = 0; h < 4; ++h)
#pragma unroll
      for (int r = 0; r < 4; ++r) {
        float e = __expf(sc[h][r] * 0.25f);
        cur[qq * 4 + r][h * 16 + m] = b16_ru(e);
      }

    // phase 5: O_h = p_un V, rowsum via ones-B MFMA
    f32x4 ot[4], rs[4];
#pragma unroll
    for (int h = 0; h < 4; ++h) {
      bf16x8 ap = *(const bf16x8*)&cur[m][h * hselA + aoffA];
      bf16x8 bv = *(const bf16x8*)&oth[m][h * 16 + boff];
      ot[h] = MFMA(ap, bv, z4);
      rs[h] = MFMA(ap, ones8, z4);
    }

    // phase 6: normalize + concat heads -> ob into cur (over p)
#pragma unroll
    for (int h = 0; h < 4; ++h)
#pragma unroll
      for (int r = 0; r < 4; ++r) {
        float o = ot[h][r] * __builtin_amdgcn_rcpf(rs[h][r]);
        cur[qq * 4 + r][h * 16 + m] = b16_ru(o);
      }

    // phase 7: x1 = LN1(x + o@Wo + bo) -> oth (over vT), xres
    {
      bf16x8 ao0 = *(const bf16x8*)&cur[m][qq * 8];
      bf16x8 ao1 = *(const bf16x8*)&cur[m][32 + qq * 8];
      f32x4 dt[4];
#pragma unroll
      for (int n = 0; n < 4; ++n) {
        const int bn = (n * 16 + m) * 64 + qq * 8;
        bf16x8 w0 = *(const bf16x8*)(TWO + bn), w1 = *(const bf16x8*)(TWO + bn + 32);
        f32x4 a = MFMA(ao0, w0, z4); dt[n] = MFMA(ao1, w1, a);
      }
      float vals[4][4];
#pragma unroll
      for (int n = 0; n < 4; ++n) {
        float bcol = bo[l * E_ + n * 16 + m];
#pragma unroll
        for (int r = 0; r < 4; ++r) vals[n][r] = xres[n][r] + dt[n][r] + bcol;
      }
      ln16(vals);
#pragma unroll
      for (int n = 0; n < 4; ++n) {
        float g = ln1g[l * E_ + n * 16 + m];
        float bb = ln1b[l * E_ + n * 16 + m];
#pragma unroll
        for (int r = 0; r < 4; ++r) {
          float xv = fmaf(vals[n][r], g, bb);
          xres[n][r] = xv;
          oth[qq * 4 + r][n * 16 + m] = b16_ru(xv);
        }
      }
    }

    // phase 8: h1 = relu(x1@W1 + b1) -> cur (over ob)
    {
      bf16x8 a10 = *(const bf16x8*)&oth[m][qq * 8];
      bf16x8 a11 = *(const bf16x8*)&oth[m][32 + qq * 8];
#pragma unroll
      for (int n = 0; n < 4; ++n) {
        const int bn = (n * 16 + m) * 64 + qq * 8;
        bf16x8 w0 = *(const bf16x8*)(TW1 + bn), w1 = *(const bf16x8*)(TW1 + bn + 32);
        f32x4 acc = MFMA(a10, w0, z4); acc = MFMA(a11, w1, acc);
        float bcol = b1[l * E_ + n * 16 + m];
#pragma unroll
        for (int r = 0; r < 4; ++r) {
          float hv = fmaxf(acc[r] + bcol, 0.f);
          cur[qq * 4 + r][n * 16 + m] = b16_ru(hv);
        }
      }
    }

    // phase 9: x = LN2(x1 + h1@W2 + b2) -> oth (over x1; residual x1 in xres)
    {
      bf16x8 a20 = *(const bf16x8*)&cur[m][qq * 8];
      bf16x8 a21 = *(const bf16x8*)&cur[m][32 + qq * 8];
      f32x4 dt[4];
#pragma unroll
      for (int n = 0; n < 4; ++n) {
        const int bn = (n * 16 + m) * 64 + qq * 8;
        bf16x8 w0 = *(const bf16x8*)(TW2 + bn), w1 = *(const bf16x8*)(TW2 + bn + 32);
        f32x4 a = MFMA(a20, w0, z4); dt[n] = MFMA(a21, w1, a);
      }
      float vals[4][4];
#pragma unroll
      for (int n = 0; n < 4; ++n) {
        float bcol = b2[l * E_ + n * 16 + m];
#pragma unroll
        for (int r = 0; r < 4; ++r) vals[n][r] = xres[n][r] + dt[n][r] + bcol;
      }
      ln16(vals);
#pragma unroll
      for (int n = 0; n < 4; ++n) {
        float g = ln2g[l * E_ + n * 16 + m];
        float bb = ln2b[l * E_ + n * 16 + m];
#pragma unroll
        for (int r = 0; r < 4; ++r) {
          float xv = fmaf(vals[n][r], g, bb);
          xres[n][r] = xv;
          oth[qq * 4 + r][n * 16 + m] = b16_ru(xv);
        }
      }
    }

    // ping-pong arenas: next layer's x is in oth
    short(*tmp)[72] = cur; cur = oth; oth = tmp;
  }

  // epilogue: logits = x @ Wout + bout (6 n-tiles), fp32 coalesced stores
  {
    bf16x8 af0 = *(const bf16x8*)&cur[m][qq * 8];
    bf16x8 af1 = *(const bf16x8*)&cur[m][32 + qq * 8];
    const short* TWOUT = wp + OFF_TWOUT;
#pragma unroll
    for (int n = 0; n < 6; ++n) {
      const int bn = (n * 16 + m) * 64 + qq * 8;
      bf16x8 w0 = *(const bf16x8*)(TWOUT + bn), w1 = *(const bf16x8*)(TWOUT + bn + 32);
      f32x4 acc = MFMA(af0, w0, z4); acc = MFMA(af1, w1, acc);
      float bcol = bout[n * 16 + m];
#pragma unroll
      for (int r = 0; r < 4; ++r)
        out[(seq * T_ + qq * 4 + r) * V_ + n * 16 + m] = acc[r] + bcol;
    }
  }
}

extern "C" void kernel_launch(void* const* d_in, const int* in_sizes, int n_in,
                              void* d_out, int out_size, void* d_ws, size_t ws_size,
                              hipStream_t stream) {
  const int*   data    = (const int*)d_in[0];
  const float* tok_emb = (const float*)d_in[1];
  const float* pos_emb = (const float*)d_in[2];
  const float* Wq      = (const float*)d_in[3];
  const float* Wk      = (const float*)d_in[4];
  const float* Wv      = (const float*)d_in[5];
  const float* Wo      = (const float*)d_in[6];
  const float* bo      = (const float*)d_in[7];
  const float* ln1g    = (const float*)d_in[8];
  const float* ln1b    = (const float*)d_in[9];
  const float* ln2g    = (const float*)d_in[10];
  const float* ln2b    = (const float*)d_in[11];
  const float* W1      = (const float*)d_in[12];
  const float* b1      = (const float*)d_in[13];
  const float* W2      = (const float*)d_in[14];
  const float* b2      = (const float*)d_in[15];
  const float* Wout    = (const float*)d_in[16];
  const float* bout    = (const float*)d_in[17];
  float* out = (float*)d_out;
  short* wp = (short*)d_ws;  // 104448*2 = 208896 B of workspace

  prep_weights<<<(PREP_TOT + 255) / 256, 256, 0, stream>>>(
      Wq, Wk, Wv, Wo, W1, W2, Wout, wp);

  const int B = in_sizes[0] / T_;  // 16384 sequences, 4 per block
  bert_mfma<<<B / 4, 256, 0, stream>>>(data, tok_emb, pos_emb, bo, ln1g, ln1b,
                                       ln2g, ln2b, b1, b2, bout, wp, out);
}

// Round 3
// 511.702 us; speedup vs baseline: 1.2844x; 1.2844x over previous
//
#include <hip/hip_runtime.h>

#define T_ 16
#define E_ 64
#define V_ 96
#define L_ 4

typedef unsigned int u32;
typedef unsigned short u16;
typedef __attribute__((ext_vector_type(8))) short bf16x8;
typedef __attribute__((ext_vector_type(4))) float f32x4;

#define MFMA(a, b, c) __builtin_amdgcn_mfma_f32_16x16x32_bf16(a, b, c, 0, 0, 0)

// ws layout (bf16/short elements): B-operand layout [n][k] per matrix
#define OFF_TQ 0
#define OFF_TK 16384
#define OFF_TV 32768
#define OFF_TWO 49152
#define OFF_TW1 65536
#define OFF_TW2 81920
#define OFF_TWOUT 98304
#define PREP_TOT 104448

__device__ __forceinline__ short f2b_rne(float f) {  // fp32 -> bf16 RNE (prep only)
  u32 u = __float_as_uint(f);
  u32 r = (u + 0x7fffu + ((u >> 16) & 1u)) >> 16;
  return (short)r;
}
__device__ __forceinline__ float b2f(short s) {
  return __uint_as_float(((u32)(u16)s) << 16);
}
// round-half-up bf16 pack: low short = bf16(a), high short = bf16(b). 3 VALU.
__device__ __forceinline__ u32 pack2_ru(float a, float b) {
  return __builtin_amdgcn_perm(__float_as_uint(a) + 0x8000u,
                               __float_as_uint(b) + 0x8000u, 0x03020706u);
}
// single-element round-half-up bf16 (same numerics as pack2_ru) for ds_write_b16
__device__ __forceinline__ short b16_ru(float f) {
  return (short)((__float_as_uint(f) + 0x8000u) >> 16);
}

// 16-lane-row reduction via DPP row_ror adds: pure VALU, zero LDS-pipe traffic.
template <int N>
__device__ __forceinline__ float ror_add(float x) {
  int y = __builtin_amdgcn_update_dpp(0, __float_as_int(x), 0x120 + N, 0xF, 0xF,
                                      true);
  return x + __int_as_float(y);
}
__device__ __forceinline__ float sum16(float x) {
  x = ror_add<8>(x);
  x = ror_add<4>(x);
  x = ror_add<2>(x);
  x = ror_add<1>(x);
  return x;
}

__global__ void __launch_bounds__(256) prep_weights(
    const float* __restrict__ Wq, const float* __restrict__ Wk,
    const float* __restrict__ Wv, const float* __restrict__ Wo,
    const float* __restrict__ W1, const float* __restrict__ W2,
    const float* __restrict__ Wout, short* __restrict__ wpo) {
  int id = blockIdx.x * 256 + threadIdx.x;
  if (id >= PREP_TOT) return;
  float v;
  if (id < OFF_TWO) {                       // TQ/TK/TV: n = h*16+kq, k = e
    int which = id >> 14;                   // 0=Q,1=K,2=V
    int r = id & 16383;
    int l = r >> 12, n = (r >> 6) & 63, e = r & 63;
    int h = n >> 4, kq = n & 15;
    const float* W = which == 0 ? Wq : (which == 1 ? Wk : Wv);
    v = W[((l * 4 + h) * 64 + e) * 16 + kq];
  } else if (id < OFF_TWOUT) {              // TWo/TW1/TW2: n = out col, k = e
    int id2 = id - OFF_TWO;
    int which = id2 >> 14;                  // 0=Wo,1=W1,2=W2
    int r = id2 & 16383;
    int l = r >> 12, n = (r >> 6) & 63, e = r & 63;
    const float* W = which == 0 ? Wo : (which == 1 ? W1 : W2);
    v = W[(l * 64 + e) * 64 + n];
  } else {                                  // TWout: n = vocab col, k = e
    int r = id - OFF_TWOUT;
    int n = r >> 6, e = r & 63;
    v = Wout[e * 96 + n];
  }
  wpo[id] = f2b_rne(v);
}

// LayerNorm over 64 cols held as 4 n-regs x 16 lanes (same qq group), rows r.
__device__ __forceinline__ void ln16(float vals[4][4]) {
#pragma unroll
  for (int r = 0; r < 4; ++r) {
    float s = vals[0][r] + vals[1][r] + vals[2][r] + vals[3][r];
    s = sum16(s);
    float mean = s * 0.015625f;
    float vv = 0.f;
#pragma unroll
    for (int n = 0; n < 4; ++n) { float d = vals[n][r] - mean; vv = fmaf(d, d, vv); }
    vv = sum16(vv);
    float rst = rsqrtf(vv * 0.015625f + 1e-5f);
#pragma unroll
    for (int n = 0; n < 4; ++n) vals[n][r] = (vals[n][r] - mean) * rst;
  }
}

// 256 threads = 4 waves; wave w handles sequence blockIdx.x*4+w. No
// __syncthreads: LDS is wave-private, DS pipe is in-order per wave.
// TWO arenas per wave -> 18432 B/block -> 8 blocks/CU (LDS-limited).
// launch_bounds(256,4): do NOT force 8 waves/EU — that squeezed VGPRs to 32
// and spilled ~1 GB to scratch (round-2 counters). At VGPR=64 the runtime
// occupancy is still 8 waves/SIMD; the bound only caps the allocator at 128.
// Time-multiplex: cur: x -> q -> p -> ob -> h1 ; oth: k -> vT -> x1 -> x(next).
// Arenas ping-pong each layer; cols 64..71 of both stay zero (A-frag upper-K pad).
__global__ void __launch_bounds__(256, 4) bert_mfma(
    const int* __restrict__ data,
    const float* __restrict__ tok_emb, const float* __restrict__ pos_emb,
    const float* __restrict__ bo, const float* __restrict__ ln1g,
    const float* __restrict__ ln1b, const float* __restrict__ ln2g,
    const float* __restrict__ ln2b, const float* __restrict__ b1,
    const float* __restrict__ b2, const float* __restrict__ bout,
    const short* __restrict__ wp, float* __restrict__ out) {
  __shared__ __align__(16) short R[4][2][16][72];

  const int w = threadIdx.x >> 6;
  const int lane = threadIdx.x & 63;
  const int m = lane & 15;   // A-row t / B-row / C-col
  const int qq = lane >> 4;  // k-chunk for frags; C rows qq*4+r
  const int seq = blockIdx.x * 4 + w;

  short(*cur)[72] = R[w][0];
  short(*oth)[72] = R[w][1];

  // zero cols 64..71 of BOTH arenas: A-frag upper-K lanes (qq>=2) read here -> 0
  if (lane < 16) {
    *(float4*)&R[w][0][lane][64] = make_float4(0.f, 0.f, 0.f, 0.f);
    *(float4*)&R[w][1][lane][64] = make_float4(0.f, 0.f, 0.f, 0.f);
  }

  // ---- embedding: x = tok_emb[data] + pos_emb -> cur bf16 [t][e] ----
  {
    const int t = lane >> 2;
    const int c0 = (lane & 3) * 16;
    const int tok = data[seq * T_ + t];
    const float4* tp = (const float4*)(tok_emb + tok * E_ + c0);
    const float4* pp = (const float4*)(pos_emb + t * E_ + c0);
    u32 buf[8];
#pragma unroll
    for (int q = 0; q < 4; ++q) {
      float4 a = tp[q], b = pp[q];
      buf[q * 2 + 0] = pack2_ru(a.x + b.x, a.y + b.y);
      buf[q * 2 + 1] = pack2_ru(a.z + b.z, a.w + b.w);
    }
    ((bf16x8*)&cur[t][c0])[0] = ((bf16x8*)buf)[0];
    *(bf16x8*)&cur[t][c0 + 8] = ((bf16x8*)(buf + 4))[0];
  }

  // residual stream, C-layout regs: xres[n][r] = x[qq*4+r][n*16+m]
  float xres[4][4];
#pragma unroll
  for (int n = 0; n < 4; ++n)
#pragma unroll
    for (int r = 0; r < 4; ++r) xres[n][r] = b2f(cur[qq * 4 + r][n * 16 + m]);

  const short s1b = (short)0x3F80;
  const bf16x8 ones8 = {s1b, s1b, s1b, s1b, s1b, s1b, s1b, s1b};
  const f32x4 z4 = {0.f, 0.f, 0.f, 0.f};
  const int hselA = (qq < 2) ? 16 : 0;               // head stride for A-frag
  const int aoffA = (qq < 2) ? ((qq & 1) * 8) : 64;  // qq>=2 -> zero cols
  const int boff = (qq & 1) * 8;  // B-frag k>=16 multiplied by A zeros

#pragma unroll 1
  for (int l = 0; l < L_; ++l) {
    const short* TQ = wp + OFF_TQ + l * 4096;
    const short* TK = wp + OFF_TK + l * 4096;
    const short* TV = wp + OFF_TV + l * 4096;
    const short* TWO = wp + OFF_TWO + l * 4096;
    const short* TW1 = wp + OFF_TW1 + l * 4096;
    const short* TW2 = wp + OFF_TW2 + l * 4096;

    // phase 1: x A-frags to regs (x in LDS dead afterwards)
    bf16x8 ax0 = *(const bf16x8*)&cur[m][qq * 8];
    bf16x8 ax1 = *(const bf16x8*)&cur[m][32 + qq * 8];

    // phase 2a: Q,K all heads (16 MFMAs); q -> cur (over x), k -> oth
#pragma unroll
    for (int h = 0; h < 4; ++h) {
      const int bn = (h * 16 + m) * 64 + qq * 8;
      bf16x8 bq0 = *(const bf16x8*)(TQ + bn), bq1 = *(const bf16x8*)(TQ + bn + 32);
      bf16x8 bk0 = *(const bf16x8*)(TK + bn), bk1 = *(const bf16x8*)(TK + bn + 32);
      f32x4 qa = MFMA(ax0, bq0, z4); qa = MFMA(ax1, bq1, qa);
      f32x4 ka = MFMA(ax0, bk0, z4); ka = MFMA(ax1, bk1, ka);
#pragma unroll
      for (int r = 0; r < 4; ++r) {
        cur[qq * 4 + r][h * 16 + m] = b16_ru(qa[r]);
        oth[qq * 4 + r][h * 16 + m] = b16_ru(ka[r]);
      }
    }

    // phase 3: S_h = q k^T (A zero-cols give K 16..31 = 0)
    f32x4 sc[4];
#pragma unroll
    for (int h = 0; h < 4; ++h) {
      bf16x8 aq = *(const bf16x8*)&cur[m][h * hselA + aoffA];
      bf16x8 bk = *(const bf16x8*)&oth[m][h * 16 + boff];
      sc[h] = MFMA(aq, bk, z4);
    }

    // phase 2b: V (8 MFMAs, independent of phase 3) -> vT into oth (over k;
    // DS pipe is in-order per wave, so these stores queue after phase-3 reads)
#pragma unroll
    for (int h = 0; h < 4; ++h) {
      const int bn = (h * 16 + m) * 64 + qq * 8;
      bf16x8 bv0 = *(const bf16x8*)(TV + bn), bv1 = *(const bf16x8*)(TV + bn + 32);
      f32x4 va = MFMA(ax0, bv0, z4); va = MFMA(ax1, bv1, va);
      // vT[kd][h*16+t]: 4 consecutive t in-lane -> one b64
      *(uint2*)&oth[m][h * 16 + qq * 4] =
          make_uint2(pack2_ru(va[0], va[1]), pack2_ru(va[2], va[3]));
    }

    // phase 4: p_un = exp(S/4) (no max-sub: |S| << 1) -> cur (over q)
#pragma unroll
    for (int h = 0; h < 4; ++h)
#pragma unroll
      for (int r = 0; r < 4; ++r) {
        float e = __expf(sc[h][r] * 0.25f);
        cur[qq * 4 + r][h * 16 + m] = b16_ru(e);
      }

    // phase 5: O_h = p_un V, rowsum via ones-B MFMA
    f32x4 ot[4], rs[4];
#pragma unroll
    for (int h = 0; h < 4; ++h) {
      bf16x8 ap = *(const bf16x8*)&cur[m][h * hselA + aoffA];
      bf16x8 bv = *(const bf16x8*)&oth[m][h * 16 + boff];
      ot[h] = MFMA(ap, bv, z4);
      rs[h] = MFMA(ap, ones8, z4);
    }

    // phase 6: normalize + concat heads -> ob into cur (over p)
#pragma unroll
    for (int h = 0; h < 4; ++h)
#pragma unroll
      for (int r = 0; r < 4; ++r) {
        float o = ot[h][r] * __builtin_amdgcn_rcpf(rs[h][r]);
        cur[qq * 4 + r][h * 16 + m] = b16_ru(o);
      }

    // phase 7: x1 = LN1(x + o@Wo + bo) -> oth (over vT), xres
    {
      bf16x8 ao0 = *(const bf16x8*)&cur[m][qq * 8];
      bf16x8 ao1 = *(const bf16x8*)&cur[m][32 + qq * 8];
      f32x4 dt[4];
#pragma unroll
      for (int n = 0; n < 4; ++n) {
        const int bn = (n * 16 + m) * 64 + qq * 8;
        bf16x8 w0 = *(const bf16x8*)(TWO + bn), w1 = *(const bf16x8*)(TWO + bn + 32);
        f32x4 a = MFMA(ao0, w0, z4); dt[n] = MFMA(ao1, w1, a);
      }
      float vals[4][4];
#pragma unroll
      for (int n = 0; n < 4; ++n) {
        float bcol = bo[l * E_ + n * 16 + m];
#pragma unroll
        for (int r = 0; r < 4; ++r) vals[n][r] = xres[n][r] + dt[n][r] + bcol;
      }
      ln16(vals);
#pragma unroll
      for (int n = 0; n < 4; ++n) {
        float g = ln1g[l * E_ + n * 16 + m];
        float bb = ln1b[l * E_ + n * 16 + m];
#pragma unroll
        for (int r = 0; r < 4; ++r) {
          float xv = fmaf(vals[n][r], g, bb);
          xres[n][r] = xv;
          oth[qq * 4 + r][n * 16 + m] = b16_ru(xv);
        }
      }
    }

    // phase 8: h1 = relu(x1@W1 + b1) -> cur (over ob)
    {
      bf16x8 a10 = *(const bf16x8*)&oth[m][qq * 8];
      bf16x8 a11 = *(const bf16x8*)&oth[m][32 + qq * 8];
#pragma unroll
      for (int n = 0; n < 4; ++n) {
        const int bn = (n * 16 + m) * 64 + qq * 8;
        bf16x8 w0 = *(const bf16x8*)(TW1 + bn), w1 = *(const bf16x8*)(TW1 + bn + 32);
        f32x4 acc = MFMA(a10, w0, z4); acc = MFMA(a11, w1, acc);
        float bcol = b1[l * E_ + n * 16 + m];
#pragma unroll
        for (int r = 0; r < 4; ++r) {
          float hv = fmaxf(acc[r] + bcol, 0.f);
          cur[qq * 4 + r][n * 16 + m] = b16_ru(hv);
        }
      }
    }

    // phase 9: x = LN2(x1 + h1@W2 + b2) -> oth (over x1; residual x1 in xres)
    {
      bf16x8 a20 = *(const bf16x8*)&cur[m][qq * 8];
      bf16x8 a21 = *(const bf16x8*)&cur[m][32 + qq * 8];
      f32x4 dt[4];
#pragma unroll
      for (int n = 0; n < 4; ++n) {
        const int bn = (n * 16 + m) * 64 + qq * 8;
        bf16x8 w0 = *(const bf16x8*)(TW2 + bn), w1 = *(const bf16x8*)(TW2 + bn + 32);
        f32x4 a = MFMA(a20, w0, z4); dt[n] = MFMA(a21, w1, a);
      }
      float vals[4][4];
#pragma unroll
      for (int n = 0; n < 4; ++n) {
        float bcol = b2[l * E_ + n * 16 + m];
#pragma unroll
        for (int r = 0; r < 4; ++r) vals[n][r] = xres[n][r] + dt[n][r] + bcol;
      }
      ln16(vals);
#pragma unroll
      for (int n = 0; n < 4; ++n) {
        float g = ln2g[l * E_ + n * 16 + m];
        float bb = ln2b[l * E_ + n * 16 + m];
#pragma unroll
        for (int r = 0; r < 4; ++r) {
          float xv = fmaf(vals[n][r], g, bb);
          xres[n][r] = xv;
          oth[qq * 4 + r][n * 16 + m] = b16_ru(xv);
        }
      }
    }

    // ping-pong arenas: next layer's x is in oth
    short(*tmp)[72] = cur; cur = oth; oth = tmp;
  }

  // epilogue: logits = x @ Wout + bout (6 n-tiles), fp32 coalesced stores
  {
    bf16x8 af0 = *(const bf16x8*)&cur[m][qq * 8];
    bf16x8 af1 = *(const bf16x8*)&cur[m][32 + qq * 8];
    const short* TWOUT = wp + OFF_TWOUT;
#pragma unroll
    for (int n = 0; n < 6; ++n) {
      const int bn = (n * 16 + m) * 64 + qq * 8;
      bf16x8 w0 = *(const bf16x8*)(TWOUT + bn), w1 = *(const bf16x8*)(TWOUT + bn + 32);
      f32x4 acc = MFMA(af0, w0, z4); acc = MFMA(af1, w1, acc);
      float bcol = bout[n * 16 + m];
#pragma unroll
      for (int r = 0; r < 4; ++r)
        out[(seq * T_ + qq * 4 + r) * V_ + n * 16 + m] = acc[r] + bcol;
    }
  }
}

extern "C" void kernel_launch(void* const* d_in, const int* in_sizes, int n_in,
                              void* d_out, int out_size, void* d_ws, size_t ws_size,
                              hipStream_t stream) {
  const int*   data    = (const int*)d_in[0];
  const float* tok_emb = (const float*)d_in[1];
  const float* pos_emb = (const float*)d_in[2];
  const float* Wq      = (const float*)d_in[3];
  const float* Wk      = (const float*)d_in[4];
  const float* Wv      = (const float*)d_in[5];
  const float* Wo      = (const float*)d_in[6];
  const float* bo      = (const float*)d_in[7];
  const float* ln1g    = (const float*)d_in[8];
  const float* ln1b    = (const float*)d_in[9];
  const float* ln2g    = (const float*)d_in[10];
  const float* ln2b    = (const float*)d_in[11];
  const float* W1      = (const float*)d_in[12];
  const float* b1      = (const float*)d_in[13];
  const float* W2      = (const float*)d_in[14];
  const float* b2      = (const float*)d_in[15];
  const float* Wout    = (const float*)d_in[16];
  const float* bout    = (const float*)d_in[17];
  float* out = (float*)d_out;
  short* wp = (short*)d_ws;  // 104448*2 = 208896 B of workspace

  prep_weights<<<(PREP_TOT + 255) / 256, 256, 0, stream>>>(
      Wq, Wk, Wv, Wo, W1, W2, Wout, wp);

  const int B = in_sizes[0] / T_;  // 16384 sequences, 4 per block
  bert_mfma<<<B / 4, 256, 0, stream>>>(data, tok_emb, pos_emb, bo, ln1g, ln1b,
                                       ln2g, ln2b, b1, b2, bout, wp, out);
}

// Round 4
// 461.504 us; speedup vs baseline: 1.4241x; 1.1088x over previous
//
#include <hip/hip_runtime.h>

#define T_ 16
#define E_ 64
#define V_ 96
#define L_ 4

typedef unsigned int u32;
typedef unsigned short u16;
typedef __attribute__((ext_vector_type(8))) short bf16x8;
typedef __attribute__((ext_vector_type(4))) float f32x4;

#define MFMA(a, b, c) __builtin_amdgcn_mfma_f32_16x16x32_bf16(a, b, c, 0, 0, 0)

// ws layout (bf16/short elements): B-operand layout [n][k] per matrix
#define OFF_TQ 0
#define OFF_TK 16384
#define OFF_TV 32768
#define OFF_TWO 49152
#define OFF_TW1 65536
#define OFF_TW2 81920
#define OFF_TWOUT 98304
#define PREP_TOT 104448

__device__ __forceinline__ short f2b_rne(float f) {  // fp32 -> bf16 RNE (prep only)
  u32 u = __float_as_uint(f);
  u32 r = (u + 0x7fffu + ((u >> 16) & 1u)) >> 16;
  return (short)r;
}
__device__ __forceinline__ float b2f(short s) {
  return __uint_as_float(((u32)(u16)s) << 16);
}
// round-half-up bf16 pack: low short = bf16(a), high short = bf16(b). 3 VALU.
__device__ __forceinline__ u32 pack2_ru(float a, float b) {
  return __builtin_amdgcn_perm(__float_as_uint(a) + 0x8000u,
                               __float_as_uint(b) + 0x8000u, 0x03020706u);
}
// single-element round-half-up bf16 (same numerics as pack2_ru) for ds_write_b16
__device__ __forceinline__ short b16_ru(float f) {
  return (short)((__float_as_uint(f) + 0x8000u) >> 16);
}

// 16-lane-row reduction via DPP row_ror adds: pure VALU, zero LDS-pipe traffic.
template <int N>
__device__ __forceinline__ float ror_add(float x) {
  int y = __builtin_amdgcn_update_dpp(0, __float_as_int(x), 0x120 + N, 0xF, 0xF,
                                      true);
  return x + __int_as_float(y);
}
__device__ __forceinline__ float sum16(float x) {
  x = ror_add<8>(x);
  x = ror_add<4>(x);
  x = ror_add<2>(x);
  x = ror_add<1>(x);
  return x;
}

__global__ void __launch_bounds__(256) prep_weights(
    const float* __restrict__ Wq, const float* __restrict__ Wk,
    const float* __restrict__ Wv, const float* __restrict__ Wo,
    const float* __restrict__ W1, const float* __restrict__ W2,
    const float* __restrict__ Wout, short* __restrict__ wpo) {
  int id = blockIdx.x * 256 + threadIdx.x;
  if (id >= PREP_TOT) return;
  float v;
  if (id < OFF_TWO) {                       // TQ/TK/TV: n = h*16+kq, k = e
    int which = id >> 14;                   // 0=Q,1=K,2=V
    int r = id & 16383;
    int l = r >> 12, n = (r >> 6) & 63, e = r & 63;
    int h = n >> 4, kq = n & 15;
    const float* W = which == 0 ? Wq : (which == 1 ? Wk : Wv);
    v = W[((l * 4 + h) * 64 + e) * 16 + kq];
  } else if (id < OFF_TWOUT) {              // TWo/TW1/TW2: n = out col, k = e
    int id2 = id - OFF_TWO;
    int which = id2 >> 14;                  // 0=Wo,1=W1,2=W2
    int r = id2 & 16383;
    int l = r >> 12, n = (r >> 6) & 63, e = r & 63;
    const float* W = which == 0 ? Wo : (which == 1 ? W1 : W2);
    v = W[(l * 64 + e) * 64 + n];
  } else {                                  // TWout: n = vocab col, k = e
    int r = id - OFF_TWOUT;
    int n = r >> 6, e = r & 63;
    v = Wout[e * 96 + n];
  }
  wpo[id] = f2b_rne(v);
}

// LayerNorm over 64 cols held as 4 n-regs x 16 lanes (same qq group), rows r.
__device__ __forceinline__ void ln16(float vals[4][4]) {
#pragma unroll
  for (int r = 0; r < 4; ++r) {
    float s = vals[0][r] + vals[1][r] + vals[2][r] + vals[3][r];
    s = sum16(s);
    float mean = s * 0.015625f;
    float vv = 0.f;
#pragma unroll
    for (int n = 0; n < 4; ++n) { float d = vals[n][r] - mean; vv = fmaf(d, d, vv); }
    vv = sum16(vv);
    float rst = rsqrtf(vv * 0.015625f + 1e-5f);
#pragma unroll
    for (int n = 0; n < 4; ++n) vals[n][r] = (vals[n][r] - mean) * rst;
  }
}

// 256 threads = 4 waves; wave w handles TWO sequences (blockIdx.x*8 + w*2 + s).
// Latency-bound fix: occupancy is VGPR-capped at ~16 waves/CU (rounds 1-3:
// VGPR 60-64 -> 47%, VGPR 32 -> 89% but spills ~1GB). So instead of more
// waves, run 2 independent per-seq chains per wave: the scheduler interleaves
// them, and both seqs share each phase's weight fragments (half the global
// loads per seq). No __syncthreads: LDS is wave-private, DS pipe in-order.
// Per seq: 2 arenas, ping-pong per layer; cols 64..71 stay zero (A-frag pad).
// LDS = 4 waves x 2 seqs x 2 arenas x 2304 B = 36864 B -> 4 blocks/CU (same
// limit VGPRs impose). launch_bounds(256,4) caps VGPR at 128.
__global__ void __launch_bounds__(256, 4) bert_mfma(
    const int* __restrict__ data,
    const float* __restrict__ tok_emb, const float* __restrict__ pos_emb,
    const float* __restrict__ bo, const float* __restrict__ ln1g,
    const float* __restrict__ ln1b, const float* __restrict__ ln2g,
    const float* __restrict__ ln2b, const float* __restrict__ b1,
    const float* __restrict__ b2, const float* __restrict__ bout,
    const short* __restrict__ wp, float* __restrict__ out) {
  __shared__ __align__(16) short R[4][2][2][16][72];  // [wave][seq][arena]

  const int w = threadIdx.x >> 6;
  const int lane = threadIdx.x & 63;
  const int m = lane & 15;   // A-row t / B-row / C-col
  const int qq = lane >> 4;  // k-chunk for frags; C rows qq*4+r
  const int seq0 = blockIdx.x * 8 + w * 2;

  short(*cur[2])[72] = {R[w][0][0], R[w][1][0]};
  short(*oth[2])[72] = {R[w][0][1], R[w][1][1]};

  // zero cols 64..71 of all 4 arenas: A-frag upper-K lanes (qq>=2) read here -> 0
  if (lane < 16) {
#pragma unroll
    for (int s = 0; s < 2; ++s) {
      *(float4*)&R[w][s][0][lane][64] = make_float4(0.f, 0.f, 0.f, 0.f);
      *(float4*)&R[w][s][1][lane][64] = make_float4(0.f, 0.f, 0.f, 0.f);
    }
  }

  // ---- embedding: x = tok_emb[data] + pos_emb -> cur[s] bf16 [t][e] ----
#pragma unroll
  for (int s = 0; s < 2; ++s) {
    const int t = lane >> 2;
    const int c0 = (lane & 3) * 16;
    const int tok = data[(seq0 + s) * T_ + t];
    const float4* tp = (const float4*)(tok_emb + tok * E_ + c0);
    const float4* pp = (const float4*)(pos_emb + t * E_ + c0);
    u32 buf[8];
#pragma unroll
    for (int q = 0; q < 4; ++q) {
      float4 a = tp[q], b = pp[q];
      buf[q * 2 + 0] = pack2_ru(a.x + b.x, a.y + b.y);
      buf[q * 2 + 1] = pack2_ru(a.z + b.z, a.w + b.w);
    }
    ((bf16x8*)&cur[s][t][c0])[0] = ((bf16x8*)buf)[0];
    *(bf16x8*)&cur[s][t][c0 + 8] = ((bf16x8*)(buf + 4))[0];
  }

  // residual stream, C-layout regs: xres[s][n][r] = x_s[qq*4+r][n*16+m]
  float xres[2][4][4];
#pragma unroll
  for (int s = 0; s < 2; ++s)
#pragma unroll
    for (int n = 0; n < 4; ++n)
#pragma unroll
      for (int r = 0; r < 4; ++r) xres[s][n][r] = b2f(cur[s][qq * 4 + r][n * 16 + m]);

  const short s1b = (short)0x3F80;
  const bf16x8 ones8 = {s1b, s1b, s1b, s1b, s1b, s1b, s1b, s1b};
  const f32x4 z4 = {0.f, 0.f, 0.f, 0.f};
  const int hselA = (qq < 2) ? 16 : 0;               // head stride for A-frag
  const int aoffA = (qq < 2) ? ((qq & 1) * 8) : 64;  // qq>=2 -> zero cols
  const int boff = (qq & 1) * 8;  // B-frag k>=16 multiplied by A zeros

#pragma unroll 1
  for (int l = 0; l < L_; ++l) {
    const short* TQ = wp + OFF_TQ + l * 4096;
    const short* TK = wp + OFF_TK + l * 4096;
    const short* TV = wp + OFF_TV + l * 4096;
    const short* TWO = wp + OFF_TWO + l * 4096;
    const short* TW1 = wp + OFF_TW1 + l * 4096;
    const short* TW2 = wp + OFF_TW2 + l * 4096;

    // phase 1: x A-frags to regs (x in LDS dead afterwards)
    bf16x8 ax0[2], ax1[2];
#pragma unroll
    for (int s = 0; s < 2; ++s) {
      ax0[s] = *(const bf16x8*)&cur[s][m][qq * 8];
      ax1[s] = *(const bf16x8*)&cur[s][m][32 + qq * 8];
    }

    // phase 2a: Q,K all heads; weights loaded ONCE, used by both seqs.
    // q -> cur (over x), k -> oth
#pragma unroll
    for (int h = 0; h < 4; ++h) {
      const int bn = (h * 16 + m) * 64 + qq * 8;
      bf16x8 bq0 = *(const bf16x8*)(TQ + bn), bq1 = *(const bf16x8*)(TQ + bn + 32);
      bf16x8 bk0 = *(const bf16x8*)(TK + bn), bk1 = *(const bf16x8*)(TK + bn + 32);
#pragma unroll
      for (int s = 0; s < 2; ++s) {
        f32x4 qa = MFMA(ax0[s], bq0, z4); qa = MFMA(ax1[s], bq1, qa);
        f32x4 ka = MFMA(ax0[s], bk0, z4); ka = MFMA(ax1[s], bk1, ka);
#pragma unroll
        for (int r = 0; r < 4; ++r) {
          cur[s][qq * 4 + r][h * 16 + m] = b16_ru(qa[r]);
          oth[s][qq * 4 + r][h * 16 + m] = b16_ru(ka[r]);
        }
      }
    }

    // phase 3+4 fused per head: S_h = q k^T, p = exp(S/4) -> cur (over q[h];
    // reads of q[h]/k[h] precede the p[h] write in-order on the DS pipe)
#pragma unroll
    for (int h = 0; h < 4; ++h) {
#pragma unroll
      for (int s = 0; s < 2; ++s) {
        bf16x8 aq = *(const bf16x8*)&cur[s][m][h * hselA + aoffA];
        bf16x8 bk = *(const bf16x8*)&oth[s][m][h * 16 + boff];
        f32x4 sc = MFMA(aq, bk, z4);
#pragma unroll
        for (int r = 0; r < 4; ++r) {
          float e = __expf(sc[r] * 0.25f);
          cur[s][qq * 4 + r][h * 16 + m] = b16_ru(e);
        }
      }
    }

    // phase 2b: V -> vT into oth (over k; all k reads done above)
#pragma unroll
    for (int h = 0; h < 4; ++h) {
      const int bn = (h * 16 + m) * 64 + qq * 8;
      bf16x8 bv0 = *(const bf16x8*)(TV + bn), bv1 = *(const bf16x8*)(TV + bn + 32);
#pragma unroll
      for (int s = 0; s < 2; ++s) {
        f32x4 va = MFMA(ax0[s], bv0, z4); va = MFMA(ax1[s], bv1, va);
        // vT[kd][h*16+t]: 4 consecutive t in-lane -> one b64
        *(uint2*)&oth[s][m][h * 16 + qq * 4] =
            make_uint2(pack2_ru(va[0], va[1]), pack2_ru(va[2], va[3]));
      }
    }

    // phase 5+6 fused per head: O_h = p V (rowsum via ones-B MFMA), normalize,
    // concat -> cur (over p[h]; p[h] reads precede the o[h] write in-order)
#pragma unroll
    for (int h = 0; h < 4; ++h) {
#pragma unroll
      for (int s = 0; s < 2; ++s) {
        bf16x8 ap = *(const bf16x8*)&cur[s][m][h * hselA + aoffA];
        bf16x8 bv = *(const bf16x8*)&oth[s][m][h * 16 + boff];
        f32x4 ot = MFMA(ap, bv, z4);
        f32x4 rs = MFMA(ap, ones8, z4);
#pragma unroll
        for (int r = 0; r < 4; ++r) {
          float o = ot[r] * __builtin_amdgcn_rcpf(rs[r]);
          cur[s][qq * 4 + r][h * 16 + m] = b16_ru(o);
        }
      }
    }

    // phase 7: x1 = LN1(x + o@Wo + bo) -> oth (over vT), xres
    {
      bf16x8 ao0[2], ao1[2];
#pragma unroll
      for (int s = 0; s < 2; ++s) {
        ao0[s] = *(const bf16x8*)&cur[s][m][qq * 8];
        ao1[s] = *(const bf16x8*)&cur[s][m][32 + qq * 8];
      }
      float vals[2][4][4];
#pragma unroll
      for (int n = 0; n < 4; ++n) {
        const int bn = (n * 16 + m) * 64 + qq * 8;
        bf16x8 w0 = *(const bf16x8*)(TWO + bn), w1 = *(const bf16x8*)(TWO + bn + 32);
        float bcol = bo[l * E_ + n * 16 + m];
#pragma unroll
        for (int s = 0; s < 2; ++s) {
          f32x4 d = MFMA(ao0[s], w0, z4); d = MFMA(ao1[s], w1, d);
#pragma unroll
          for (int r = 0; r < 4; ++r) vals[s][n][r] = xres[s][n][r] + d[r] + bcol;
        }
      }
#pragma unroll
      for (int s = 0; s < 2; ++s) ln16(vals[s]);
#pragma unroll
      for (int n = 0; n < 4; ++n) {
        float g = ln1g[l * E_ + n * 16 + m];
        float bb = ln1b[l * E_ + n * 16 + m];
#pragma unroll
        for (int s = 0; s < 2; ++s)
#pragma unroll
          for (int r = 0; r < 4; ++r) {
            float xv = fmaf(vals[s][n][r], g, bb);
            xres[s][n][r] = xv;
            oth[s][qq * 4 + r][n * 16 + m] = b16_ru(xv);
          }
      }
    }

    // phase 8: h1 = relu(x1@W1 + b1) -> cur (over ob)
    {
      bf16x8 a10[2], a11[2];
#pragma unroll
      for (int s = 0; s < 2; ++s) {
        a10[s] = *(const bf16x8*)&oth[s][m][qq * 8];
        a11[s] = *(const bf16x8*)&oth[s][m][32 + qq * 8];
      }
#pragma unroll
      for (int n = 0; n < 4; ++n) {
        const int bn = (n * 16 + m) * 64 + qq * 8;
        bf16x8 w0 = *(const bf16x8*)(TW1 + bn), w1 = *(const bf16x8*)(TW1 + bn + 32);
        float bcol = b1[l * E_ + n * 16 + m];
#pragma unroll
        for (int s = 0; s < 2; ++s) {
          f32x4 acc = MFMA(a10[s], w0, z4); acc = MFMA(a11[s], w1, acc);
#pragma unroll
          for (int r = 0; r < 4; ++r) {
            float hv = fmaxf(acc[r] + bcol, 0.f);
            cur[s][qq * 4 + r][n * 16 + m] = b16_ru(hv);
          }
        }
      }
    }

    // phase 9: x = LN2(x1 + h1@W2 + b2) -> oth (over x1; residual x1 in xres)
    {
      bf16x8 a20[2], a21[2];
#pragma unroll
      for (int s = 0; s < 2; ++s) {
        a20[s] = *(const bf16x8*)&cur[s][m][qq * 8];
        a21[s] = *(const bf16x8*)&cur[s][m][32 + qq * 8];
      }
      float vals[2][4][4];
#pragma unroll
      for (int n = 0; n < 4; ++n) {
        const int bn = (n * 16 + m) * 64 + qq * 8;
        bf16x8 w0 = *(const bf16x8*)(TW2 + bn), w1 = *(const bf16x8*)(TW2 + bn + 32);
        float bcol = b2[l * E_ + n * 16 + m];
#pragma unroll
        for (int s = 0; s < 2; ++s) {
          f32x4 d = MFMA(a20[s], w0, z4); d = MFMA(a21[s], w1, d);
#pragma unroll
          for (int r = 0; r < 4; ++r) vals[s][n][r] = xres[s][n][r] + d[r] + bcol;
        }
      }
#pragma unroll
      for (int s = 0; s < 2; ++s) ln16(vals[s]);
#pragma unroll
      for (int n = 0; n < 4; ++n) {
        float g = ln2g[l * E_ + n * 16 + m];
        float bb = ln2b[l * E_ + n * 16 + m];
#pragma unroll
        for (int s = 0; s < 2; ++s)
#pragma unroll
          for (int r = 0; r < 4; ++r) {
            float xv = fmaf(vals[s][n][r], g, bb);
            xres[s][n][r] = xv;
            oth[s][qq * 4 + r][n * 16 + m] = b16_ru(xv);
          }
      }
    }

    // ping-pong arenas: next layer's x is in oth
#pragma unroll
    for (int s = 0; s < 2; ++s) {
      short(*tmp)[72] = cur[s]; cur[s] = oth[s]; oth[s] = tmp;
    }
  }

  // epilogue: logits = x @ Wout + bout (6 n-tiles), fp32 coalesced stores
  {
    bf16x8 af0[2], af1[2];
#pragma unroll
    for (int s = 0; s < 2; ++s) {
      af0[s] = *(const bf16x8*)&cur[s][m][qq * 8];
      af1[s] = *(const bf16x8*)&cur[s][m][32 + qq * 8];
    }
    const short* TWOUT = wp + OFF_TWOUT;
#pragma unroll
    for (int n = 0; n < 6; ++n) {
      const int bn = (n * 16 + m) * 64 + qq * 8;
      bf16x8 w0 = *(const bf16x8*)(TWOUT + bn), w1 = *(const bf16x8*)(TWOUT + bn + 32);
      float bcol = bout[n * 16 + m];
#pragma unroll
      for (int s = 0; s < 2; ++s) {
        f32x4 acc = MFMA(af0[s], w0, z4); acc = MFMA(af1[s], w1, acc);
#pragma unroll
        for (int r = 0; r < 4; ++r)
          out[((seq0 + s) * T_ + qq * 4 + r) * V_ + n * 16 + m] = acc[r] + bcol;
      }
    }
  }
}

extern "C" void kernel_launch(void* const* d_in, const int* in_sizes, int n_in,
                              void* d_out, int out_size, void* d_ws, size_t ws_size,
                              hipStream_t stream) {
  const int*   data    = (const int*)d_in[0];
  const float* tok_emb = (const float*)d_in[1];
  const float* pos_emb = (const float*)d_in[2];
  const float* Wq      = (const float*)d_in[3];
  const float* Wk      = (const float*)d_in[4];
  const float* Wv      = (const float*)d_in[5];
  const float* Wo      = (const float*)d_in[6];
  const float* bo      = (const float*)d_in[7];
  const float* ln1g    = (const float*)d_in[8];
  const float* ln1b    = (const float*)d_in[9];
  const float* ln2g    = (const float*)d_in[10];
  const float* ln2b    = (const float*)d_in[11];
  const float* W1      = (const float*)d_in[12];
  const float* b1      = (const float*)d_in[13];
  const float* W2      = (const float*)d_in[14];
  const float* b2      = (const float*)d_in[15];
  const float* Wout    = (const float*)d_in[16];
  const float* bout    = (const float*)d_in[17];
  float* out = (float*)d_out;
  short* wp = (short*)d_ws;  // 104448*2 = 208896 B of workspace

  prep_weights<<<(PREP_TOT + 255) / 256, 256, 0, stream>>>(
      Wq, Wk, Wv, Wo, W1, W2, Wout, wp);

  const int B = in_sizes[0] / T_;  // 16384 sequences, 8 per block (2 per wave)
  bert_mfma<<<B / 8, 256, 0, stream>>>(data, tok_emb, pos_emb, bo, ln1g, ln1b,
                                       ln2g, ln2b, b1, b2, bout, wp, out);
}

// Round 5
// 460.850 us; speedup vs baseline: 1.4261x; 1.0014x over previous
//
#include <hip/hip_runtime.h>

#define T_ 16
#define E_ 64
#define V_ 96
#define L_ 4

typedef unsigned int u32;
typedef unsigned short u16;
typedef __attribute__((ext_vector_type(8))) short bf16x8;
typedef __attribute__((ext_vector_type(4))) float f32x4;

#define MFMA(a, b, c) __builtin_amdgcn_mfma_f32_16x16x32_bf16(a, b, c, 0, 0, 0)

// ws layout (bf16/short elements): B-operand layout [n][k] per matrix
#define OFF_TQ 0
#define OFF_TK 16384
#define OFF_TV 32768
#define OFF_TWO 49152
#define OFF_TW1 65536
#define OFF_TW2 81920
#define OFF_TWOUT 98304
#define PREP_TOT 104448

__device__ __forceinline__ short f2b_rne(float f) {  // fp32 -> bf16 RNE (prep only)
  u32 u = __float_as_uint(f);
  u32 r = (u + 0x7fffu + ((u >> 16) & 1u)) >> 16;
  return (short)r;
}
__device__ __forceinline__ float b2f(short s) {
  return __uint_as_float(((u32)(u16)s) << 16);
}
// round-half-up bf16 pack: low short = bf16(a), high short = bf16(b). 3 VALU.
__device__ __forceinline__ u32 pack2_ru(float a, float b) {
  return __builtin_amdgcn_perm(__float_as_uint(a) + 0x8000u,
                               __float_as_uint(b) + 0x8000u, 0x03020706u);
}
// single-element round-half-up bf16 (same numerics as pack2_ru) for ds_write_b16
__device__ __forceinline__ short b16_ru(float f) {
  return (short)((__float_as_uint(f) + 0x8000u) >> 16);
}

// 16-lane-row reduction via DPP row_ror adds: pure VALU, zero LDS-pipe traffic.
template <int N>
__device__ __forceinline__ float ror_add(float x) {
  int y = __builtin_amdgcn_update_dpp(0, __float_as_int(x), 0x120 + N, 0xF, 0xF,
                                      true);
  return x + __int_as_float(y);
}
__device__ __forceinline__ float sum16(float x) {
  x = ror_add<8>(x);
  x = ror_add<4>(x);
  x = ror_add<2>(x);
  x = ror_add<1>(x);
  return x;
}

__global__ void __launch_bounds__(256) prep_weights(
    const float* __restrict__ Wq, const float* __restrict__ Wk,
    const float* __restrict__ Wv, const float* __restrict__ Wo,
    const float* __restrict__ W1, const float* __restrict__ W2,
    const float* __restrict__ Wout, short* __restrict__ wpo) {
  int id = blockIdx.x * 256 + threadIdx.x;
  if (id >= PREP_TOT) return;
  float v;
  if (id < OFF_TWO) {                       // TQ/TK/TV: n = h*16+kq, k = e
    int which = id >> 14;                   // 0=Q,1=K,2=V
    int r = id & 16383;
    int l = r >> 12, n = (r >> 6) & 63, e = r & 63;
    int h = n >> 4, kq = n & 15;
    const float* W = which == 0 ? Wq : (which == 1 ? Wk : Wv);
    v = W[((l * 4 + h) * 64 + e) * 16 + kq];
  } else if (id < OFF_TWOUT) {              // TWo/TW1/TW2: n = out col, k = e
    int id2 = id - OFF_TWO;
    int which = id2 >> 14;                  // 0=Wo,1=W1,2=W2
    int r = id2 & 16383;
    int l = r >> 12, n = (r >> 6) & 63, e = r & 63;
    const float* W = which == 0 ? Wo : (which == 1 ? W1 : W2);
    v = W[(l * 64 + e) * 64 + n];
  } else {                                  // TWout: n = vocab col, k = e
    int r = id - OFF_TWOUT;
    int n = r >> 6, e = r & 63;
    v = Wout[e * 96 + n];
  }
  wpo[id] = f2b_rne(v);
}

// LayerNorm over 64 cols held as 4 n-regs x 16 lanes (same qq group), rows r.
__device__ __forceinline__ void ln16(float vals[4][4]) {
#pragma unroll
  for (int r = 0; r < 4; ++r) {
    float s = vals[0][r] + vals[1][r] + vals[2][r] + vals[3][r];
    s = sum16(s);
    float mean = s * 0.015625f;
    float vv = 0.f;
#pragma unroll
    for (int n = 0; n < 4; ++n) { float d = vals[n][r] - mean; vv = fmaf(d, d, vv); }
    vv = sum16(vv);
    float rst = rsqrtf(vv * 0.015625f + 1e-5f);
#pragma unroll
    for (int n = 0; n < 4; ++n) vals[n][r] = (vals[n][r] - mean) * rst;
  }
}

// 256 threads = 4 waves; wave w handles TWO sequences (blockIdx.x*8 + w*2 + s).
// Occupancy is VGPR/LDS-capped at 4 waves/EU; 2 independent per-seq chains per
// wave provide the latency hiding instead of extra waves, and both seqs share
// each phase's weight fragments. No __syncthreads: LDS wave-private, DS pipe
// in-order per wave. Per seq: 2 arenas, ping-pong per layer; cols 64..71 zero.
// amdgpu_waves_per_eu(4,4): pin the allocator's occupancy TARGET to 4 waves/EU
// (cap 128 VGPR). Round 4 proved launch_bounds(256,4) only sets the MIN — the
// allocator chased 8 waves/EU (64 VGPR) on its own and spilled ~440 MB to
// scratch (FETCH 172 MB / WRITE 367 MB). LDS caps runtime occupancy at 4
// waves/EU anyway, so max=4 costs nothing.
__global__ void __launch_bounds__(256)
__attribute__((amdgpu_waves_per_eu(4, 4))) bert_mfma(
    const int* __restrict__ data,
    const float* __restrict__ tok_emb, const float* __restrict__ pos_emb,
    const float* __restrict__ bo, const float* __restrict__ ln1g,
    const float* __restrict__ ln1b, const float* __restrict__ ln2g,
    const float* __restrict__ ln2b, const float* __restrict__ b1,
    const float* __restrict__ b2, const float* __restrict__ bout,
    const short* __restrict__ wp, float* __restrict__ out) {
  __shared__ __align__(16) short R[4][2][2][16][72];  // [wave][seq][arena]

  const int w = threadIdx.x >> 6;
  const int lane = threadIdx.x & 63;
  const int m = lane & 15;   // A-row t / B-row / C-col
  const int qq = lane >> 4;  // k-chunk for frags; C rows qq*4+r
  const int seq0 = blockIdx.x * 8 + w * 2;

  short(*cur[2])[72] = {R[w][0][0], R[w][1][0]};
  short(*oth[2])[72] = {R[w][0][1], R[w][1][1]};

  // zero cols 64..71 of all 4 arenas: A-frag upper-K lanes (qq>=2) read here -> 0
  if (lane < 16) {
#pragma unroll
    for (int s = 0; s < 2; ++s) {
      *(float4*)&R[w][s][0][lane][64] = make_float4(0.f, 0.f, 0.f, 0.f);
      *(float4*)&R[w][s][1][lane][64] = make_float4(0.f, 0.f, 0.f, 0.f);
    }
  }

  // ---- embedding: x = tok_emb[data] + pos_emb -> cur[s] bf16 [t][e] ----
#pragma unroll
  for (int s = 0; s < 2; ++s) {
    const int t = lane >> 2;
    const int c0 = (lane & 3) * 16;
    const int tok = data[(seq0 + s) * T_ + t];
    const float4* tp = (const float4*)(tok_emb + tok * E_ + c0);
    const float4* pp = (const float4*)(pos_emb + t * E_ + c0);
    u32 buf[8];
#pragma unroll
    for (int q = 0; q < 4; ++q) {
      float4 a = tp[q], b = pp[q];
      buf[q * 2 + 0] = pack2_ru(a.x + b.x, a.y + b.y);
      buf[q * 2 + 1] = pack2_ru(a.z + b.z, a.w + b.w);
    }
    ((bf16x8*)&cur[s][t][c0])[0] = ((bf16x8*)buf)[0];
    *(bf16x8*)&cur[s][t][c0 + 8] = ((bf16x8*)(buf + 4))[0];
  }

  // residual stream, C-layout regs: xres[s][n][r] = x_s[qq*4+r][n*16+m]
  float xres[2][4][4];
#pragma unroll
  for (int s = 0; s < 2; ++s)
#pragma unroll
    for (int n = 0; n < 4; ++n)
#pragma unroll
      for (int r = 0; r < 4; ++r) xres[s][n][r] = b2f(cur[s][qq * 4 + r][n * 16 + m]);

  const short s1b = (short)0x3F80;
  const bf16x8 ones8 = {s1b, s1b, s1b, s1b, s1b, s1b, s1b, s1b};
  const f32x4 z4 = {0.f, 0.f, 0.f, 0.f};
  const int hselA = (qq < 2) ? 16 : 0;               // head stride for A-frag
  const int aoffA = (qq < 2) ? ((qq & 1) * 8) : 64;  // qq>=2 -> zero cols
  const int boff = (qq & 1) * 8;  // B-frag k>=16 multiplied by A zeros

#pragma unroll 1
  for (int l = 0; l < L_; ++l) {
    const short* TQ = wp + OFF_TQ + l * 4096;
    const short* TK = wp + OFF_TK + l * 4096;
    const short* TV = wp + OFF_TV + l * 4096;
    const short* TWO = wp + OFF_TWO + l * 4096;
    const short* TW1 = wp + OFF_TW1 + l * 4096;
    const short* TW2 = wp + OFF_TW2 + l * 4096;

    // phase 1: x A-frags to regs (x in LDS dead afterwards)
    bf16x8 ax0[2], ax1[2];
#pragma unroll
    for (int s = 0; s < 2; ++s) {
      ax0[s] = *(const bf16x8*)&cur[s][m][qq * 8];
      ax1[s] = *(const bf16x8*)&cur[s][m][32 + qq * 8];
    }

    // phase 2a: Q,K all heads; weights loaded ONCE, used by both seqs.
    // q -> cur (over x), k -> oth
#pragma unroll
    for (int h = 0; h < 4; ++h) {
      const int bn = (h * 16 + m) * 64 + qq * 8;
      bf16x8 bq0 = *(const bf16x8*)(TQ + bn), bq1 = *(const bf16x8*)(TQ + bn + 32);
      bf16x8 bk0 = *(const bf16x8*)(TK + bn), bk1 = *(const bf16x8*)(TK + bn + 32);
#pragma unroll
      for (int s = 0; s < 2; ++s) {
        f32x4 qa = MFMA(ax0[s], bq0, z4); qa = MFMA(ax1[s], bq1, qa);
        f32x4 ka = MFMA(ax0[s], bk0, z4); ka = MFMA(ax1[s], bk1, ka);
#pragma unroll
        for (int r = 0; r < 4; ++r) {
          cur[s][qq * 4 + r][h * 16 + m] = b16_ru(qa[r]);
          oth[s][qq * 4 + r][h * 16 + m] = b16_ru(ka[r]);
        }
      }
    }

    // phase 3+4 fused per head: S_h = q k^T, p = exp(S/4) -> cur (over q[h];
    // reads of q[h]/k[h] precede the p[h] write in-order on the DS pipe)
#pragma unroll
    for (int h = 0; h < 4; ++h) {
#pragma unroll
      for (int s = 0; s < 2; ++s) {
        bf16x8 aq = *(const bf16x8*)&cur[s][m][h * hselA + aoffA];
        bf16x8 bk = *(const bf16x8*)&oth[s][m][h * 16 + boff];
        f32x4 sc = MFMA(aq, bk, z4);
#pragma unroll
        for (int r = 0; r < 4; ++r) {
          float e = __expf(sc[r] * 0.25f);
          cur[s][qq * 4 + r][h * 16 + m] = b16_ru(e);
        }
      }
    }

    // phase 2b: V -> vT into oth (over k; all k reads done above)
#pragma unroll
    for (int h = 0; h < 4; ++h) {
      const int bn = (h * 16 + m) * 64 + qq * 8;
      bf16x8 bv0 = *(const bf16x8*)(TV + bn), bv1 = *(const bf16x8*)(TV + bn + 32);
#pragma unroll
      for (int s = 0; s < 2; ++s) {
        f32x4 va = MFMA(ax0[s], bv0, z4); va = MFMA(ax1[s], bv1, va);
        // vT[kd][h*16+t]: 4 consecutive t in-lane -> one b64
        *(uint2*)&oth[s][m][h * 16 + qq * 4] =
            make_uint2(pack2_ru(va[0], va[1]), pack2_ru(va[2], va[3]));
      }
    }

    // phase 5+6 fused per head: O_h = p V (rowsum via ones-B MFMA), normalize,
    // concat -> cur (over p[h]; p[h] reads precede the o[h] write in-order)
#pragma unroll
    for (int h = 0; h < 4; ++h) {
#pragma unroll
      for (int s = 0; s < 2; ++s) {
        bf16x8 ap = *(const bf16x8*)&cur[s][m][h * hselA + aoffA];
        bf16x8 bv = *(const bf16x8*)&oth[s][m][h * 16 + boff];
        f32x4 ot = MFMA(ap, bv, z4);
        f32x4 rs = MFMA(ap, ones8, z4);
#pragma unroll
        for (int r = 0; r < 4; ++r) {
          float o = ot[r] * __builtin_amdgcn_rcpf(rs[r]);
          cur[s][qq * 4 + r][h * 16 + m] = b16_ru(o);
        }
      }
    }

    // phase 7: x1 = LN1(x + o@Wo + bo) -> oth (over vT), xres
    {
      bf16x8 ao0[2], ao1[2];
#pragma unroll
      for (int s = 0; s < 2; ++s) {
        ao0[s] = *(const bf16x8*)&cur[s][m][qq * 8];
        ao1[s] = *(const bf16x8*)&cur[s][m][32 + qq * 8];
      }
      float vals[2][4][4];
#pragma unroll
      for (int n = 0; n < 4; ++n) {
        const int bn = (n * 16 + m) * 64 + qq * 8;
        bf16x8 w0 = *(const bf16x8*)(TWO + bn), w1 = *(const bf16x8*)(TWO + bn + 32);
        float bcol = bo[l * E_ + n * 16 + m];
#pragma unroll
        for (int s = 0; s < 2; ++s) {
          f32x4 d = MFMA(ao0[s], w0, z4); d = MFMA(ao1[s], w1, d);
#pragma unroll
          for (int r = 0; r < 4; ++r) vals[s][n][r] = xres[s][n][r] + d[r] + bcol;
        }
      }
#pragma unroll
      for (int s = 0; s < 2; ++s) ln16(vals[s]);
#pragma unroll
      for (int n = 0; n < 4; ++n) {
        float g = ln1g[l * E_ + n * 16 + m];
        float bb = ln1b[l * E_ + n * 16 + m];
#pragma unroll
        for (int s = 0; s < 2; ++s)
#pragma unroll
          for (int r = 0; r < 4; ++r) {
            float xv = fmaf(vals[s][n][r], g, bb);
            xres[s][n][r] = xv;
            oth[s][qq * 4 + r][n * 16 + m] = b16_ru(xv);
          }
      }
    }

    // phase 8: h1 = relu(x1@W1 + b1) -> cur (over ob)
    {
      bf16x8 a10[2], a11[2];
#pragma unroll
      for (int s = 0; s < 2; ++s) {
        a10[s] = *(const bf16x8*)&oth[s][m][qq * 8];
        a11[s] = *(const bf16x8*)&oth[s][m][32 + qq * 8];
      }
#pragma unroll
      for (int n = 0; n < 4; ++n) {
        const int bn = (n * 16 + m) * 64 + qq * 8;
        bf16x8 w0 = *(const bf16x8*)(TW1 + bn), w1 = *(const bf16x8*)(TW1 + bn + 32);
        float bcol = b1[l * E_ + n * 16 + m];
#pragma unroll
        for (int s = 0; s < 2; ++s) {
          f32x4 acc = MFMA(a10[s], w0, z4); acc = MFMA(a11[s], w1, acc);
#pragma unroll
          for (int r = 0; r < 4; ++r) {
            float hv = fmaxf(acc[r] + bcol, 0.f);
            cur[s][qq * 4 + r][n * 16 + m] = b16_ru(hv);
          }
        }
      }
    }

    // phase 9: x = LN2(x1 + h1@W2 + b2) -> oth (over x1; residual x1 in xres)
    {
      bf16x8 a20[2], a21[2];
#pragma unroll
      for (int s = 0; s < 2; ++s) {
        a20[s] = *(const bf16x8*)&cur[s][m][qq * 8];
        a21[s] = *(const bf16x8*)&cur[s][m][32 + qq * 8];
      }
      float vals[2][4][4];
#pragma unroll
      for (int n = 0; n < 4; ++n) {
        const int bn = (n * 16 + m) * 64 + qq * 8;
        bf16x8 w0 = *(const bf16x8*)(TW2 + bn), w1 = *(const bf16x8*)(TW2 + bn + 32);
        float bcol = b2[l * E_ + n * 16 + m];
#pragma unroll
        for (int s = 0; s < 2; ++s) {
          f32x4 d = MFMA(a20[s], w0, z4); d = MFMA(a21[s], w1, d);
#pragma unroll
          for (int r = 0; r < 4; ++r) vals[s][n][r] = xres[s][n][r] + d[r] + bcol;
        }
      }
#pragma unroll
      for (int s = 0; s < 2; ++s) ln16(vals[s]);
#pragma unroll
      for (int n = 0; n < 4; ++n) {
        float g = ln2g[l * E_ + n * 16 + m];
        float bb = ln2b[l * E_ + n * 16 + m];
#pragma unroll
        for (int s = 0; s < 2; ++s)
#pragma unroll
          for (int r = 0; r < 4; ++r) {
            float xv = fmaf(vals[s][n][r], g, bb);
            xres[s][n][r] = xv;
            oth[s][qq * 4 + r][n * 16 + m] = b16_ru(xv);
          }
      }
    }

    // ping-pong arenas: next layer's x is in oth
#pragma unroll
    for (int s = 0; s < 2; ++s) {
      short(*tmp)[72] = cur[s]; cur[s] = oth[s]; oth[s] = tmp;
    }
  }

  // epilogue: logits = x @ Wout + bout (6 n-tiles), fp32 coalesced stores
  {
    bf16x8 af0[2], af1[2];
#pragma unroll
    for (int s = 0; s < 2; ++s) {
      af0[s] = *(const bf16x8*)&cur[s][m][qq * 8];
      af1[s] = *(const bf16x8*)&cur[s][m][32 + qq * 8];
    }
    const short* TWOUT = wp + OFF_TWOUT;
#pragma unroll
    for (int n = 0; n < 6; ++n) {
      const int bn = (n * 16 + m) * 64 + qq * 8;
      bf16x8 w0 = *(const bf16x8*)(TWOUT + bn), w1 = *(const bf16x8*)(TWOUT + bn + 32);
      float bcol = bout[n * 16 + m];
#pragma unroll
      for (int s = 0; s < 2; ++s) {
        f32x4 acc = MFMA(af0[s], w0, z4); acc = MFMA(af1[s], w1, acc);
#pragma unroll
        for (int r = 0; r < 4; ++r)
          out[((seq0 + s) * T_ + qq * 4 + r) * V_ + n * 16 + m] = acc[r] + bcol;
      }
    }
  }
}

extern "C" void kernel_launch(void* const* d_in, const int* in_sizes, int n_in,
                              void* d_out, int out_size, void* d_ws, size_t ws_size,
                              hipStream_t stream) {
  const int*   data    = (const int*)d_in[0];
  const float* tok_emb = (const float*)d_in[1];
  const float* pos_emb = (const float*)d_in[2];
  const float* Wq      = (const float*)d_in[3];
  const float* Wk      = (const float*)d_in[4];
  const float* Wv      = (const float*)d_in[5];
  const float* Wo      = (const float*)d_in[6];
  const float* bo      = (const float*)d_in[7];
  const float* ln1g    = (const float*)d_in[8];
  const float* ln1b    = (const float*)d_in[9];
  const float* ln2g    = (const float*)d_in[10];
  const float* ln2b    = (const float*)d_in[11];
  const float* W1      = (const float*)d_in[12];
  const float* b1      = (const float*)d_in[13];
  const float* W2      = (const float*)d_in[14];
  const float* b2      = (const float*)d_in[15];
  const float* Wout    = (const float*)d_in[16];
  const float* bout    = (const float*)d_in[17];
  float* out = (float*)d_out;
  short* wp = (short*)d_ws;  // 104448*2 = 208896 B of workspace

  prep_weights<<<(PREP_TOT + 255) / 256, 256, 0, stream>>>(
      Wq, Wk, Wv, Wo, W1, W2, Wout, wp);

  const int B = in_sizes[0] / T_;  // 16384 sequences, 8 per block (2 per wave)
  bert_mfma<<<B / 8, 256, 0, stream>>>(data, tok_emb, pos_emb, bo, ln1g, ln1b,
                                       ln2g, ln2b, b1, b2, bout, wp, out);
}